// Round 2
// baseline (295.922 us; speedup 1.0000x reference)
//
#include <hip/hip_runtime.h>

// B=4, S=2048, D=1024, H=16, DK=64. RoPE (interleaved pairs) + causal MHA.
// R3: attention rewrite — no-max softmax, K=16 PV MFMA, merged (qt,31-qt)
// q-tile pairs, SCALE folded into q at RoPE.
// R4: attn3 double-buffered K/V prefetch + XCD-grouping block remap.
// R5 (this round): gemm128 2-phase pipeline — double-buffered LDS (64KB),
// stage(kt+1) issued BEFORE compute(kt) so L2/HBM latency hides under the
// MFMA phase; one barrier per K-step (was 2 + full drain). Plus bijective
// XCD chunking of the block id so each XCD's L2 keeps its own W panels.

typedef unsigned short u16;
typedef unsigned int u32;
typedef __attribute__((ext_vector_type(8))) short bf16x8;
typedef __attribute__((ext_vector_type(4))) short bf16x4;
typedef __attribute__((ext_vector_type(4))) float f32x4;
typedef __attribute__((ext_vector_type(4))) unsigned short u16x4;

#define S_LEN 2048
#define DMODEL 1024
#define NHEAD 16
#define DKH 64
#define BATCH 4
#define NT 32  // S_LEN/64 key tiles

static __device__ __forceinline__ u16 f2bf(float f) {
  union { float f; u32 u; } v; v.f = f;
  u32 r = v.u + 0x7fffu + ((v.u >> 16) & 1u);  // RNE
  return (u16)(r >> 16);
}
#if __has_builtin(__builtin_amdgcn_cvt_pk_bf16_f32)
typedef __attribute__((ext_vector_type(2))) __bf16 bf2_t;
static __device__ __forceinline__ u32 pack2bf(float a, float b) {
  union { bf2_t h; u32 u; } cv;
  cv.h = __builtin_amdgcn_cvt_pk_bf16_f32(a, b);
  return cv.u;
}
#else
static __device__ __forceinline__ u32 pack2bf(float a, float b) {
  return (u32)f2bf(a) | ((u32)f2bf(b) << 16);
}
#endif
static __device__ __forceinline__ float fexp2(float x) {
#if __has_builtin(__builtin_amdgcn_exp2f)
  return __builtin_amdgcn_exp2f(x);
#else
  return exp2f(x);
#endif
}
static __device__ __forceinline__ f32x4 mfma16(bf16x8 a, bf16x8 b, f32x4 c) {
  return __builtin_amdgcn_mfma_f32_16x16x32_bf16(a, b, c, 0, 0, 0);
}
#if __has_builtin(__builtin_amdgcn_mfma_f32_16x16x16bf16_1k)
#define HAVE_MFMA_K16 1
static __device__ __forceinline__ f32x4 mfma16k16(bf16x4 a, bf16x4 b, f32x4 c) {
  return __builtin_amdgcn_mfma_f32_16x16x16bf16_1k(a, b, c, 0, 0, 0);
}
#else
#define HAVE_MFMA_K16 0
#endif
// Async global->LDS, 16B per lane. LDS dest = wave-uniform base + lane*16.
static __device__ __forceinline__ void glds16(const void* g, void* l) {
  __builtin_amdgcn_global_load_lds((const __attribute__((address_space(1))) u32*)g,
                                   (__attribute__((address_space(3))) u32*)l, 16, 0, 0);
}

__global__ __launch_bounds__(256) void cast_bf16(const float* __restrict__ src,
                                                 u16* __restrict__ dst, int n4) {
  int i = blockIdx.x * 256 + threadIdx.x;
  if (i >= n4) return;
  const float* s = src + (size_t)i * 4;
  u16x4 o;
  o.x = f2bf(s[0]); o.y = f2bf(s[1]); o.z = f2bf(s[2]); o.w = f2bf(s[3]);
  ((u16x4*)dst)[i] = o;
}

// C[m,n] = sum_k A[m,k] * W[n,k]. 128x128 tile, BK=64, glds staging,
// 2-phase double-buffered pipeline: stage tile kt+1 into buf^1 BEFORE the
// MFMA phase on buf (prefetch latency hides under compute); single
// __syncthreads per K-step does the vmcnt(0)+barrier.
// mode 0: QKV epilogue (n<1024 -> oq, <2048 -> ok, else ov as [B,H,DK,S]).
// mode 2: fp32 store to of.
__global__ __launch_bounds__(256) void gemm128(const u16* __restrict__ A,
                                               const u16* __restrict__ W,
                                               u16* __restrict__ oq,
                                               u16* __restrict__ ok,
                                               u16* __restrict__ ov,
                                               float* __restrict__ of,
                                               int mode) {
  __shared__ __attribute__((aligned(16))) u16 As[2][128 * 64];
  __shared__ __attribute__((aligned(16))) u16 Bs[2][128 * 64];
  // Bijective XCD chunking: nwg%8==0 for both launches (1536, 512). Each
  // XCD gets a contiguous chunk of the original id space -> consecutive
  // (same-W-panel) blocks share one XCD's L2.
  const int nwg = gridDim.x * gridDim.y;
  const int L = blockIdx.y * gridDim.x + blockIdx.x;
  const int wg = (L & 7) * (nwg >> 3) + (L >> 3);
  const int m0 = (wg % gridDim.x) * 128, n0 = (wg / gridDim.x) * 128;
  const int tid = threadIdx.x, lane = tid & 63, wave = tid >> 6;
  const int quad = lane >> 4, c = lane & 15;
  const int wm = (wave & 1) * 64, wn = (wave >> 1) * 64;
  const int ls = lane >> 3, lc = lane & 7;

  auto stage = [&](int buf, int ko) {
#pragma unroll
    for (int i = 0; i < 4; ++i) {
      int rb = i * 32 + wave * 8;
      int r = rb + ls;
      int kA = ko + 8 * (lc ^ (r & 7));
      glds16(&A[(size_t)(m0 + r) * DMODEL + kA], &As[buf][rb * 64]);
      glds16(&W[(size_t)(n0 + r) * DMODEL + kA], &Bs[buf][rb * 64]);
    }
  };

  f32x4 acc[4][4] = {};
  stage(0, 0);
  __syncthreads();
#pragma unroll 1
  for (int kt = 0; kt < DMODEL / 64; ++kt) {
    const int cur = kt & 1;
    if (kt < DMODEL / 64 - 1) stage(cur ^ 1, (kt + 1) * 64);  // prefetch, no wait
#pragma unroll
    for (int t = 0; t < 2; ++t) {
      bf16x8 af[4], bfr[4];
#pragma unroll
      for (int mb = 0; mb < 4; ++mb) {
        int r = wm + mb * 16 + c;
        af[mb] = *(const bf16x8*)&As[cur][r * 64 + 8 * ((t * 4 + quad) ^ (r & 7))];
      }
#pragma unroll
      for (int nb = 0; nb < 4; ++nb) {
        int r = wn + nb * 16 + c;
        bfr[nb] = *(const bf16x8*)&Bs[cur][r * 64 + 8 * ((t * 4 + quad) ^ (r & 7))];
      }
#pragma unroll
      for (int mb = 0; mb < 4; ++mb)
#pragma unroll
        for (int nb = 0; nb < 4; ++nb)
          acc[mb][nb] = mfma16(af[mb], bfr[nb], acc[mb][nb]);
    }
    __syncthreads();  // vmcnt(0)+barrier: prefetched buffer ready for kt+1
  }
#pragma unroll
  for (int mb = 0; mb < 4; ++mb) {
    int mrow = m0 + wm + mb * 16 + quad * 4;
#pragma unroll
    for (int nb = 0; nb < 4; ++nb) {
      int n = n0 + wn + nb * 16 + c;
      f32x4 v = acc[mb][nb];
      if (mode == 2) {
#pragma unroll
        for (int r = 0; r < 4; ++r) of[(size_t)(mrow + r) * DMODEL + n] = v[r];
      } else if (n < DMODEL) {
#pragma unroll
        for (int r = 0; r < 4; ++r) oq[(size_t)(mrow + r) * DMODEL + n] = f2bf(v[r]);
      } else if (n < 2 * DMODEL) {
#pragma unroll
        for (int r = 0; r < 4; ++r) ok[(size_t)(mrow + r) * DMODEL + (n - DMODEL)] = f2bf(v[r]);
      } else {
        int nn = n - 2 * DMODEL;
        int h = nn >> 6, d = nn & 63;
        int b = mrow >> 11, s = mrow & (S_LEN - 1);
        u16x4 p4;
        p4.x = f2bf(v[0]); p4.y = f2bf(v[1]); p4.z = f2bf(v[2]); p4.w = f2bf(v[3]);
        *(u16x4*)&ov[((size_t)(b * NHEAD + h) * DKH + d) * S_LEN + s] = p4;
      }
    }
  }
}

// In-place RoPE on q and k; q additionally pre-scaled by 0.125*log2(e) so
// attention scores exit QK^T MFMA directly in the log2 domain.
__global__ __launch_bounds__(256) void rope_qk(u16* __restrict__ q, u16* __restrict__ k,
                                               const int* __restrict__ pos) {
  const float QSCALE = 0.18033688011112042f;  // 0.125 * log2(e)
  int i = blockIdx.x * 256 + threadIdx.x;  // pair index over [8192][512]
  if (i >= BATCH * S_LEN * DMODEL / 2) return;
  int m = i >> 9;
  int pr = i & 511;
  int p = pr & 31;
  int s = m & (S_LEN - 1);
  float ph = (float)pos[s] * powf(10000.0f, -(float)(2 * p) / 64.0f);
  float sn, cs;
  sincosf(ph, &sn, &cs);
  unsigned vq = ((unsigned*)q)[i];
  float x1, x2, r1, r2;
  { union { u32 u; float f; } a, b2; a.u = vq << 16; b2.u = vq & 0xffff0000u;
    x1 = a.f; x2 = b2.f; }
  r1 = (x1 * cs - x2 * sn) * QSCALE; r2 = (x1 * sn + x2 * cs) * QSCALE;
  ((unsigned*)q)[i] = pack2bf(r1, r2);
  unsigned vk = ((unsigned*)k)[i];
  { union { u32 u; float f; } a, b2; a.u = vk << 16; b2.u = vk & 0xffff0000u;
    x1 = a.f; x2 = b2.f; }
  r1 = x1 * cs - x2 * sn; r2 = x1 * sn + x2 * cs;
  ((unsigned*)k)[i] = pack2bf(r1, r2);
}

// Flash attention, S^T formulation, no-max softmax.
// Grid (NT/2, B*H). Linear launch id L is remapped so the 16 q-tile-pair
// blocks of one (b,h) all land on ONE XCD (XCD = L%8 round-robin): each
// XCD's L2 then holds 8 heads' K/V (8 x 512KB = 4MB) and staging becomes
// L2-hit instead of HBM re-fetch. K/V double-buffered in LDS: stage j+1 is
// issued BEFORE apply(j) so the load latency hides under compute; one
// barrier per tile (was two).
// Wave w owns q-columns wq+c; softmax state scalar/lane. PV uses K=16 MFMA:
// P^T C-layout (keys quad*4+r, col q=c) IS the 16x16x16 B-operand layout.
__global__ __launch_bounds__(256) void attn3(const u16* __restrict__ qb,
                                             const u16* __restrict__ kb,
                                             const u16* __restrict__ vt,
                                             u16* __restrict__ ab) {
  __shared__ __attribute__((aligned(16))) u16 Ks[2][64 * 64];  // [key][d] swizzled
  __shared__ __attribute__((aligned(16))) u16 Vs[2][64 * 64];  // [d][key] swizzled
  // Bijective XCD-grouping remap (1024 blocks, 1024%8==0).
  const int L = blockIdx.x + (NT / 2) * blockIdx.y;  // launch linear id
  const int xcd = L & 7, slot = L >> 3;              // XCD = L%8 (round-robin)
  const int bh = xcd * 8 + (slot >> 4);              // 8 heads per XCD
  const int qt1 = slot & 15, qt2 = NT - 1 - qt1;
  const int b = bh >> 4, h = bh & 15;
  const int tid = threadIdx.x, lane = tid & 63, wave = tid >> 6;
  const int quad = lane >> 4, c = lane & 15;
  const int ls = lane >> 3, lc = lane & 7;
  const int wq = wave * 16;
  const float NEG = -3.0e38f;

  bf16x8 qf[2][2];
#pragma unroll
  for (int t = 0; t < 2; ++t) {
    int qrow = (t ? qt2 : qt1) * 64 + wq + c;
    const u16* qp = qb + (size_t)(b * S_LEN + qrow) * DMODEL + h * DKH;
    qf[t][0] = *(const bf16x8*)&qp[quad * 8];
    qf[t][1] = *(const bf16x8*)&qp[32 + quad * 8];
  }
  float li[2] = {0.f, 0.f};
  f32x4 od[2][4] = {};

  // issue the 4 glds16 for tile j into buffer buf (no wait here)
  auto stage = [&](int buf, int j) {
#pragma unroll
    for (int i = 0; i < 2; ++i) {
      int rb = i * 32 + wave * 8;
      int r = rb + ls;
      int col = 8 * (lc ^ (r & 7));
      glds16(&kb[(size_t)(b * S_LEN + j * 64 + r) * DMODEL + h * DKH + col], &Ks[buf][rb * 64]);
      glds16(&vt[((size_t)bh * DKH + r) * S_LEN + j * 64 + col], &Vs[buf][rb * 64]);
    }
  };

  // one q-tile application against the K/V tile staged in buffer cur
  auto apply = [&](int t, int cur, bool diag) {
    f32x4 sc[4];
#pragma unroll
    for (int kbi = 0; kbi < 4; ++kbi) {
      int r = kbi * 16 + c;
      bf16x8 k0 = *(const bf16x8*)&Ks[cur][r * 64 + 8 * (quad ^ (r & 7))];
      bf16x8 k1 = *(const bf16x8*)&Ks[cur][r * 64 + 8 * ((4 + quad) ^ (r & 7))];
      f32x4 a = {};
      a = mfma16(k0, qf[t][0], a);
      a = mfma16(k1, qf[t][1], a);
      sc[kbi] = a;  // already log2-domain (q pre-scaled)
    }
    if (diag) {
#pragma unroll
      for (int kbi = 0; kbi < 4; ++kbi)
#pragma unroll
        for (int r = 0; r < 4; ++r)
          if (kbi * 16 + quad * 4 + r > wq + c) sc[kbi][r] = NEG;
    }
    float rs = 0.f;
#pragma unroll
    for (int kbi = 0; kbi < 4; ++kbi)
#pragma unroll
      for (int r = 0; r < 4; ++r) {
        float p = fexp2(sc[kbi][r]);
        sc[kbi][r] = p;
        rs += p;
      }
    rs += __shfl_xor(rs, 16);
    rs += __shfl_xor(rs, 32);
    li[t] += rs;
#if HAVE_MFMA_K16
    // pk[kbi] = keys kbi*16+quad*4+{0,1,2,3} for q-col c == 16x16x16 B-frag
    bf16x4 pkv[4];
#pragma unroll
    for (int kbi = 0; kbi < 4; ++kbi) {
      union { u32 w[2]; bf16x4 v; } pk;
      pk.w[0] = pack2bf(sc[kbi][0], sc[kbi][1]);
      pk.w[1] = pack2bf(sc[kbi][2], sc[kbi][3]);
      pkv[kbi] = pk.v;
    }
#pragma unroll
    for (int db = 0; db < 4; ++db) {
      int r = db * 16 + c;
#pragma unroll
      for (int kbi = 0; kbi < 4; ++kbi) {
        int g = kbi * 2 + (quad >> 1);
        bf16x4 vf = *(const bf16x4*)&Vs[cur][r * 64 + 8 * (g ^ (r & 7)) + (quad & 1) * 4];
        od[t][db] = mfma16k16(vf, pkv[kbi], od[t][db]);
      }
    }
#else
    // fallback: shuffle P^T into K=32 B-frag layout
    u32 pk[4][2];
#pragma unroll
    for (int kbi = 0; kbi < 4; ++kbi) {
      pk[kbi][0] = pack2bf(sc[kbi][0], sc[kbi][1]);
      pk[kbi][1] = pack2bf(sc[kbi][2], sc[kbi][3]);
    }
    const int s0 = ((quad & 1) * 2) * 16 + c;
    const int s1 = s0 + 16;
    const bool hi = quad >= 2;
#pragma unroll
    for (int base = 0; base < 2; ++base) {
      u32 e0 = __shfl(pk[base * 2][0], s0);
      u32 e1 = __shfl(pk[base * 2][1], s0);
      u32 e2 = __shfl(pk[base * 2][0], s1);
      u32 e3 = __shfl(pk[base * 2][1], s1);
      u32 o0 = __shfl(pk[base * 2 + 1][0], s0);
      u32 o1 = __shfl(pk[base * 2 + 1][1], s0);
      u32 o2 = __shfl(pk[base * 2 + 1][0], s1);
      u32 o3 = __shfl(pk[base * 2 + 1][1], s1);
      union { u32 w[4]; bf16x8 v; } pf;
      pf.w[0] = hi ? o0 : e0;
      pf.w[1] = hi ? o1 : e1;
      pf.w[2] = hi ? o2 : e2;
      pf.w[3] = hi ? o3 : e3;
#pragma unroll
      for (int db = 0; db < 4; ++db) {
        int r = db * 16 + c;
        bf16x8 vf = *(const bf16x8*)&Vs[cur][r * 64 + 8 * ((base * 4 + quad) ^ (c & 7))];
        od[t][db] = mfma16(vf, pf.v, od[t][db]);
      }
    }
#endif
  };

  // prologue: stage tile 0 into buffer 0, wait (syncthreads drains vmcnt)
  stage(0, 0);
  __syncthreads();
#pragma unroll 1
  for (int j = 0; j <= qt2; ++j) {
    int cur = j & 1;
    if (j < qt2) stage(cur ^ 1, j + 1);  // prefetch next tile, no wait
    if (j <= qt1) apply(0, cur, j == qt1);
    apply(1, cur, j == qt2);
    __syncthreads();  // vmcnt(0)+lgkmcnt(0)+barrier: next buffer ready
  }

#pragma unroll
  for (int t = 0; t < 2; ++t) {
    float inv = 1.0f / li[t];
    int qrow = (t ? qt2 : qt1) * 64 + wq + c;
    u16* op = ab + (size_t)(b * S_LEN + qrow) * DMODEL + h * DKH;
#pragma unroll
    for (int db = 0; db < 4; ++db) {
      u16x4 o4;
      o4.x = f2bf(od[t][db][0] * inv);
      o4.y = f2bf(od[t][db][1] * inv);
      o4.z = f2bf(od[t][db][2] * inv);
      o4.w = f2bf(od[t][db][3] * inv);
      *(u16x4*)&op[db * 16 + quad * 4] = o4;
    }
  }
}

extern "C" void kernel_launch(void* const* d_in, const int* in_sizes, int n_in,
                              void* d_out, int out_size, void* d_ws, size_t ws_size,
                              hipStream_t stream) {
  const float* x = (const float*)d_in[0];
  const int* pos = (const int*)d_in[1];
  const float* Wq = (const float*)d_in[2];
  const float* Wk = (const float*)d_in[3];
  const float* Wv = (const float*)d_in[4];
  const float* Wo = (const float*)d_in[5];
  float* out = (float*)d_out;

  char* w = (char*)d_ws;
  size_t o = 0;
  auto take = [&](size_t nbytes) {
    char* p = w + o;
    o += (nbytes + 255) & ~(size_t)255;
    return p;
  };
  const size_t actBytes = (size_t)BATCH * S_LEN * DMODEL * 2;
  const size_t wBytes = (size_t)DMODEL * DMODEL * 2;
  u16* xb   = (u16*)take(actBytes);
  u16* Wcat = (u16*)take(3 * wBytes);  // [3072][1024] = Wq;Wk;Wv
  u16* Wob  = (u16*)take(wBytes);
  u16* qb   = (u16*)take(actBytes);
  u16* kb   = (u16*)take(actBytes);
  u16* vt   = (u16*)take(actBytes);  // [B,H,DK,S]
  u16* ab   = (u16*)take(actBytes);

  int n4x = BATCH * S_LEN * DMODEL / 4;
  cast_bf16<<<(n4x + 255) / 256, 256, 0, stream>>>(x, xb, n4x);
  int n4w = DMODEL * DMODEL / 4;
  cast_bf16<<<(n4w + 255) / 256, 256, 0, stream>>>(Wq, Wcat, n4w);
  cast_bf16<<<(n4w + 255) / 256, 256, 0, stream>>>(Wk, Wcat + (size_t)DMODEL * DMODEL, n4w);
  cast_bf16<<<(n4w + 255) / 256, 256, 0, stream>>>(Wv, Wcat + 2 * (size_t)DMODEL * DMODEL, n4w);
  cast_bf16<<<(n4w + 255) / 256, 256, 0, stream>>>(Wo, Wob, n4w);

  // Fused QKV: [8192,1024] x [3072,1024]^T
  gemm128<<<dim3(BATCH * S_LEN / 128, 3 * DMODEL / 128), 256, 0, stream>>>(
      xb, Wcat, qb, kb, vt, nullptr, 0);

  int npair = BATCH * S_LEN * DMODEL / 2;
  rope_qk<<<(npair + 255) / 256, 256, 0, stream>>>(qb, kb, pos);

  attn3<<<dim3(NT / 2, BATCH * NHEAD), 256, 0, stream>>>(qb, kb, vt, ab);

  gemm128<<<dim3(BATCH * S_LEN / 128, DMODEL / 128), 256, 0, stream>>>(
      ab, Wob, nullptr, nullptr, nullptr, out, 2);
}

// Round 3
// 288.982 us; speedup vs baseline: 1.0240x; 1.0240x over previous
//
#include <hip/hip_runtime.h>

// B=4, S=2048, D=1024, H=16, DK=64. RoPE (interleaved pairs) + causal MHA.
// R3: attention rewrite — no-max softmax, K=16 PV MFMA, merged (qt,31-qt)
// q-tile pairs, SCALE folded into q at RoPE.
// R4: attn3 double-buffered K/V prefetch + XCD-grouping block remap.
// R5: gemm128 2-phase pipeline (dbuf LDS, prefetch-before-compute) + XCD chunk.
// R6 (this round): attn3 512-thread blocks owning TWO q-tile pairs (waves 0-3
// pair A=(2x,31-2x), waves 4-7 pair B=(2x+1,30-2x)): one staged K/V tile now
// feeds 2x the applies -> stage latency better hidden, L2->LDS traffic halved.
// Complementary-x tail balancing per CU. setprio(1) around MFMA clusters.
// 5 cast launches fused into one cast_all kernel.

typedef unsigned short u16;
typedef unsigned int u32;
typedef __attribute__((ext_vector_type(8))) short bf16x8;
typedef __attribute__((ext_vector_type(4))) short bf16x4;
typedef __attribute__((ext_vector_type(4))) float f32x4;
typedef __attribute__((ext_vector_type(4))) unsigned short u16x4;

#define S_LEN 2048
#define DMODEL 1024
#define NHEAD 16
#define DKH 64
#define BATCH 4
#define NT 32  // S_LEN/64 key tiles
#define NX4 (BATCH * S_LEN * DMODEL / 4)  // 2097152
#define NW4 (DMODEL * DMODEL / 4)         // 262144 = 2^18

static __device__ __forceinline__ u16 f2bf(float f) {
  union { float f; u32 u; } v; v.f = f;
  u32 r = v.u + 0x7fffu + ((v.u >> 16) & 1u);  // RNE
  return (u16)(r >> 16);
}
#if __has_builtin(__builtin_amdgcn_cvt_pk_bf16_f32)
typedef __attribute__((ext_vector_type(2))) __bf16 bf2_t;
static __device__ __forceinline__ u32 pack2bf(float a, float b) {
  union { bf2_t h; u32 u; } cv;
  cv.h = __builtin_amdgcn_cvt_pk_bf16_f32(a, b);
  return cv.u;
}
#else
static __device__ __forceinline__ u32 pack2bf(float a, float b) {
  return (u32)f2bf(a) | ((u32)f2bf(b) << 16);
}
#endif
static __device__ __forceinline__ float fexp2(float x) {
#if __has_builtin(__builtin_amdgcn_exp2f)
  return __builtin_amdgcn_exp2f(x);
#else
  return exp2f(x);
#endif
}
static __device__ __forceinline__ f32x4 mfma16(bf16x8 a, bf16x8 b, f32x4 c) {
  return __builtin_amdgcn_mfma_f32_16x16x32_bf16(a, b, c, 0, 0, 0);
}
#if __has_builtin(__builtin_amdgcn_mfma_f32_16x16x16bf16_1k)
#define HAVE_MFMA_K16 1
static __device__ __forceinline__ f32x4 mfma16k16(bf16x4 a, bf16x4 b, f32x4 c) {
  return __builtin_amdgcn_mfma_f32_16x16x16bf16_1k(a, b, c, 0, 0, 0);
}
#else
#define HAVE_MFMA_K16 0
#endif
// Async global->LDS, 16B per lane. LDS dest = wave-uniform base + lane*16.
static __device__ __forceinline__ void glds16(const void* g, void* l) {
  __builtin_amdgcn_global_load_lds((const __attribute__((address_space(1))) u32*)g,
                                   (__attribute__((address_space(3))) u32*)l, 16, 0, 0);
}

// One fused cast pass: x (8M f32) + Wq,Wk,Wv -> Wcat + Wo -> Wob.
__global__ __launch_bounds__(256) void cast_all(const float* __restrict__ x,
                                                const float* __restrict__ Wq,
                                                const float* __restrict__ Wk,
                                                const float* __restrict__ Wv,
                                                const float* __restrict__ Wo,
                                                u16* __restrict__ xb,
                                                u16* __restrict__ Wcat,
                                                u16* __restrict__ Wob) {
  int i = blockIdx.x * 256 + threadIdx.x;
  const float* s;
  u16* d;
  if (i < NX4) {
    s = x + (size_t)i * 4;
    d = xb + (size_t)i * 4;
  } else {
    int j = i - NX4;
    int r = j >> 18;
    int off = j & (NW4 - 1);
    const float* W = r == 0 ? Wq : r == 1 ? Wk : r == 2 ? Wv : Wo;
    s = W + (size_t)off * 4;
    d = (r < 3 ? Wcat + (size_t)r * DMODEL * DMODEL : Wob) + (size_t)off * 4;
  }
  u16x4 o;
  o.x = f2bf(s[0]); o.y = f2bf(s[1]); o.z = f2bf(s[2]); o.w = f2bf(s[3]);
  *(u16x4*)d = o;
}

// C[m,n] = sum_k A[m,k] * W[n,k]. 128x128 tile, BK=64, glds staging,
// 2-phase double-buffered pipeline: stage tile kt+1 into buf^1 BEFORE the
// MFMA phase on buf (prefetch latency hides under compute); single
// __syncthreads per K-step does the vmcnt(0)+barrier.
// mode 0: QKV epilogue (n<1024 -> oq, <2048 -> ok, else ov as [B,H,DK,S]).
// mode 2: fp32 store to of.
__global__ __launch_bounds__(256) void gemm128(const u16* __restrict__ A,
                                               const u16* __restrict__ W,
                                               u16* __restrict__ oq,
                                               u16* __restrict__ ok,
                                               u16* __restrict__ ov,
                                               float* __restrict__ of,
                                               int mode) {
  __shared__ __attribute__((aligned(16))) u16 As[2][128 * 64];
  __shared__ __attribute__((aligned(16))) u16 Bs[2][128 * 64];
  // Bijective XCD chunking: nwg%8==0 for both launches (1536, 512).
  const int nwg = gridDim.x * gridDim.y;
  const int L = blockIdx.y * gridDim.x + blockIdx.x;
  const int wg = (L & 7) * (nwg >> 3) + (L >> 3);
  const int m0 = (wg % gridDim.x) * 128, n0 = (wg / gridDim.x) * 128;
  const int tid = threadIdx.x, lane = tid & 63, wave = tid >> 6;
  const int quad = lane >> 4, c = lane & 15;
  const int wm = (wave & 1) * 64, wn = (wave >> 1) * 64;
  const int ls = lane >> 3, lc = lane & 7;

  auto stage = [&](int buf, int ko) {
#pragma unroll
    for (int i = 0; i < 4; ++i) {
      int rb = i * 32 + wave * 8;
      int r = rb + ls;
      int kA = ko + 8 * (lc ^ (r & 7));
      glds16(&A[(size_t)(m0 + r) * DMODEL + kA], &As[buf][rb * 64]);
      glds16(&W[(size_t)(n0 + r) * DMODEL + kA], &Bs[buf][rb * 64]);
    }
  };

  f32x4 acc[4][4] = {};
  stage(0, 0);
  __syncthreads();
#pragma unroll 1
  for (int kt = 0; kt < DMODEL / 64; ++kt) {
    const int cur = kt & 1;
    if (kt < DMODEL / 64 - 1) stage(cur ^ 1, (kt + 1) * 64);  // prefetch, no wait
#pragma unroll
    for (int t = 0; t < 2; ++t) {
      bf16x8 af[4], bfr[4];
#pragma unroll
      for (int mb = 0; mb < 4; ++mb) {
        int r = wm + mb * 16 + c;
        af[mb] = *(const bf16x8*)&As[cur][r * 64 + 8 * ((t * 4 + quad) ^ (r & 7))];
      }
#pragma unroll
      for (int nb = 0; nb < 4; ++nb) {
        int r = wn + nb * 16 + c;
        bfr[nb] = *(const bf16x8*)&Bs[cur][r * 64 + 8 * ((t * 4 + quad) ^ (r & 7))];
      }
#pragma unroll
      for (int mb = 0; mb < 4; ++mb)
#pragma unroll
        for (int nb = 0; nb < 4; ++nb)
          acc[mb][nb] = mfma16(af[mb], bfr[nb], acc[mb][nb]);
    }
    __syncthreads();  // vmcnt(0)+barrier: prefetched buffer ready for kt+1
  }
#pragma unroll
  for (int mb = 0; mb < 4; ++mb) {
    int mrow = m0 + wm + mb * 16 + quad * 4;
#pragma unroll
    for (int nb = 0; nb < 4; ++nb) {
      int n = n0 + wn + nb * 16 + c;
      f32x4 v = acc[mb][nb];
      if (mode == 2) {
#pragma unroll
        for (int r = 0; r < 4; ++r) of[(size_t)(mrow + r) * DMODEL + n] = v[r];
      } else if (n < DMODEL) {
#pragma unroll
        for (int r = 0; r < 4; ++r) oq[(size_t)(mrow + r) * DMODEL + n] = f2bf(v[r]);
      } else if (n < 2 * DMODEL) {
#pragma unroll
        for (int r = 0; r < 4; ++r) ok[(size_t)(mrow + r) * DMODEL + (n - DMODEL)] = f2bf(v[r]);
      } else {
        int nn = n - 2 * DMODEL;
        int h = nn >> 6, d = nn & 63;
        int b = mrow >> 11, s = mrow & (S_LEN - 1);
        u16x4 p4;
        p4.x = f2bf(v[0]); p4.y = f2bf(v[1]); p4.z = f2bf(v[2]); p4.w = f2bf(v[3]);
        *(u16x4*)&ov[((size_t)(b * NHEAD + h) * DKH + d) * S_LEN + s] = p4;
      }
    }
  }
}

// In-place RoPE on q and k; q additionally pre-scaled by 0.125*log2(e) so
// attention scores exit QK^T MFMA directly in the log2 domain.
__global__ __launch_bounds__(256) void rope_qk(u16* __restrict__ q, u16* __restrict__ k,
                                               const int* __restrict__ pos) {
  const float QSCALE = 0.18033688011112042f;  // 0.125 * log2(e)
  int i = blockIdx.x * 256 + threadIdx.x;  // pair index over [8192][512]
  if (i >= BATCH * S_LEN * DMODEL / 2) return;
  int m = i >> 9;
  int pr = i & 511;
  int p = pr & 31;
  int s = m & (S_LEN - 1);
  float ph = (float)pos[s] * powf(10000.0f, -(float)(2 * p) / 64.0f);
  float sn, cs;
  sincosf(ph, &sn, &cs);
  unsigned vq = ((unsigned*)q)[i];
  float x1, x2, r1, r2;
  { union { u32 u; float f; } a, b2; a.u = vq << 16; b2.u = vq & 0xffff0000u;
    x1 = a.f; x2 = b2.f; }
  r1 = (x1 * cs - x2 * sn) * QSCALE; r2 = (x1 * sn + x2 * cs) * QSCALE;
  ((unsigned*)q)[i] = pack2bf(r1, r2);
  unsigned vk = ((unsigned*)k)[i];
  { union { u32 u; float f; } a, b2; a.u = vk << 16; b2.u = vk & 0xffff0000u;
    x1 = a.f; x2 = b2.f; }
  r1 = x1 * cs - x2 * sn; r2 = x1 * sn + x2 * cs;
  ((unsigned*)k)[i] = pack2bf(r1, r2);
}

// Flash attention, S^T formulation, no-max softmax.
// Grid (8, B*H), 512 threads. Block handles TWO merged q-tile pairs:
//   waves 0-3: pair A = (2x, 31-2x)    (33 applies)
//   waves 4-7: pair B = (2x+1, 30-2x)  (33 applies, idle only at j=J)
// One K/V tile staged per iteration feeds both pairs -> 2x applies per
// stage vs R4 (latency hiding), half the L2->LDS traffic. XCD remap keeps
// each (b,h)'s 8 blocks on one XCD (L2-resident K/V). x mirrored in upper
// slot half so a CU's two resident blocks get complementary iteration
// counts (placement heuristic, speed-only). setprio(1) around MFMA.
__global__ __launch_bounds__(512) void attn3(const u16* __restrict__ qb,
                                             const u16* __restrict__ kb,
                                             const u16* __restrict__ vt,
                                             u16* __restrict__ ab) {
  __shared__ __attribute__((aligned(16))) u16 Ks[2][64 * 64];  // [key][d] swizzled
  __shared__ __attribute__((aligned(16))) u16 Vs[2][64 * 64];  // [d][key] swizzled
  // 512 blocks total; XCD = L%8; 8 blocks per (b,h), 8 (b,h) per XCD.
  const int L = blockIdx.x + 8 * blockIdx.y;
  const int xcd = L & 7, slot = L >> 3;   // slot in [0,64)
  const int bhl = slot >> 3;              // local head in [0,8)
  const int xs = slot & 7;
  const int x = (bhl & 4) ? 7 - xs : xs;  // complementary-x tail balance
  const int bh = xcd * 8 + bhl;
  const int b = bh >> 4, h = bh & 15;
  const int tid = threadIdx.x, lane = tid & 63, wave = tid >> 6;
  const int g = wave >> 2;   // 0: pair A, 1: pair B
  const int w4 = wave & 3;   // q-col group within tile
  const int quad = lane >> 4, c = lane & 15;
  const int ls = lane >> 3, lc = lane & 7;
  const int wq = w4 * 16;
  const int qtl = 2 * x + g, qth = 31 - 2 * x - g;
  const int J = 31 - 2 * x;  // loop bound = pair A's qt2
  const float NEG = -3.0e38f;

  bf16x8 qf[2][2];
#pragma unroll
  for (int t = 0; t < 2; ++t) {
    int qrow = (t ? qth : qtl) * 64 + wq + c;
    const u16* qp = qb + (size_t)(b * S_LEN + qrow) * DMODEL + h * DKH;
    qf[t][0] = *(const bf16x8*)&qp[quad * 8];
    qf[t][1] = *(const bf16x8*)&qp[32 + quad * 8];
  }
  float li[2] = {0.f, 0.f};
  f32x4 od[2][4] = {};

  // stage tile j into buffer buf: 8 waves x 8 rows each (K and V), no wait
  auto stage = [&](int buf, int j) {
    int r = wave * 8 + ls;
    int col = 8 * (lc ^ (r & 7));
    glds16(&kb[(size_t)(b * S_LEN + j * 64 + r) * DMODEL + h * DKH + col],
           &Ks[buf][wave * 8 * 64]);
    glds16(&vt[((size_t)bh * DKH + r) * S_LEN + j * 64 + col],
           &Vs[buf][wave * 8 * 64]);
  };

  // one q-tile application against the K/V tile staged in buffer cur
  auto apply = [&](int t, int cur, bool diag) {
    f32x4 sc[4];
    __builtin_amdgcn_s_setprio(1);
#pragma unroll
    for (int kbi = 0; kbi < 4; ++kbi) {
      int r = kbi * 16 + c;
      bf16x8 k0 = *(const bf16x8*)&Ks[cur][r * 64 + 8 * (quad ^ (r & 7))];
      bf16x8 k1 = *(const bf16x8*)&Ks[cur][r * 64 + 8 * ((4 + quad) ^ (r & 7))];
      f32x4 a = {};
      a = mfma16(k0, qf[t][0], a);
      a = mfma16(k1, qf[t][1], a);
      sc[kbi] = a;  // already log2-domain (q pre-scaled)
    }
    __builtin_amdgcn_s_setprio(0);
    if (diag) {
#pragma unroll
      for (int kbi = 0; kbi < 4; ++kbi)
#pragma unroll
        for (int r = 0; r < 4; ++r)
          if (kbi * 16 + quad * 4 + r > wq + c) sc[kbi][r] = NEG;
    }
    float rs = 0.f;
#pragma unroll
    for (int kbi = 0; kbi < 4; ++kbi)
#pragma unroll
      for (int r = 0; r < 4; ++r) {
        float p = fexp2(sc[kbi][r]);
        sc[kbi][r] = p;
        rs += p;
      }
    rs += __shfl_xor(rs, 16);
    rs += __shfl_xor(rs, 32);
    li[t] += rs;
#if HAVE_MFMA_K16
    // pk[kbi] = keys kbi*16+quad*4+{0,1,2,3} for q-col c == 16x16x16 B-frag
    bf16x4 pkv[4];
#pragma unroll
    for (int kbi = 0; kbi < 4; ++kbi) {
      union { u32 w[2]; bf16x4 v; } pk;
      pk.w[0] = pack2bf(sc[kbi][0], sc[kbi][1]);
      pk.w[1] = pack2bf(sc[kbi][2], sc[kbi][3]);
      pkv[kbi] = pk.v;
    }
    __builtin_amdgcn_s_setprio(1);
#pragma unroll
    for (int db = 0; db < 4; ++db) {
      int r = db * 16 + c;
#pragma unroll
      for (int kbi = 0; kbi < 4; ++kbi) {
        int g2 = kbi * 2 + (quad >> 1);
        bf16x4 vf = *(const bf16x4*)&Vs[cur][r * 64 + 8 * (g2 ^ (r & 7)) + (quad & 1) * 4];
        od[t][db] = mfma16k16(vf, pkv[kbi], od[t][db]);
      }
    }
    __builtin_amdgcn_s_setprio(0);
#else
    // fallback: shuffle P^T into K=32 B-frag layout
    u32 pk[4][2];
#pragma unroll
    for (int kbi = 0; kbi < 4; ++kbi) {
      pk[kbi][0] = pack2bf(sc[kbi][0], sc[kbi][1]);
      pk[kbi][1] = pack2bf(sc[kbi][2], sc[kbi][3]);
    }
    const int s0 = ((quad & 1) * 2) * 16 + c;
    const int s1 = s0 + 16;
    const bool hi = quad >= 2;
#pragma unroll
    for (int base = 0; base < 2; ++base) {
      u32 e0 = __shfl(pk[base * 2][0], s0);
      u32 e1 = __shfl(pk[base * 2][1], s0);
      u32 e2 = __shfl(pk[base * 2][0], s1);
      u32 e3 = __shfl(pk[base * 2][1], s1);
      u32 o0 = __shfl(pk[base * 2 + 1][0], s0);
      u32 o1 = __shfl(pk[base * 2 + 1][1], s0);
      u32 o2 = __shfl(pk[base * 2 + 1][0], s1);
      u32 o3 = __shfl(pk[base * 2 + 1][1], s1);
      union { u32 w[4]; bf16x8 v; } pf;
      pf.w[0] = hi ? o0 : e0;
      pf.w[1] = hi ? o1 : e1;
      pf.w[2] = hi ? o2 : e2;
      pf.w[3] = hi ? o3 : e3;
#pragma unroll
      for (int db = 0; db < 4; ++db) {
        int r = db * 16 + c;
        bf16x8 vf = *(const bf16x8*)&Vs[cur][r * 64 + 8 * ((base * 4 + quad) ^ (c & 7))];
        od[t][db] = mfma16(vf, pf.v, od[t][db]);
      }
    }
#endif
  };

  // prologue: stage tile 0 into buffer 0, wait (syncthreads drains vmcnt)
  stage(0, 0);
  __syncthreads();
#pragma unroll 1
  for (int j = 0; j <= J; ++j) {
    int cur = j & 1;
    if (j < J) stage(cur ^ 1, j + 1);  // prefetch next tile, no wait
    if (j <= qtl) apply(0, cur, j == qtl);
    if (j <= qth) apply(1, cur, j == qth);
    __syncthreads();  // vmcnt(0)+lgkmcnt(0)+barrier: next buffer ready
  }

#pragma unroll
  for (int t = 0; t < 2; ++t) {
    float inv = 1.0f / li[t];
    int qrow = (t ? qth : qtl) * 64 + wq + c;
    u16* op = ab + (size_t)(b * S_LEN + qrow) * DMODEL + h * DKH;
#pragma unroll
    for (int db = 0; db < 4; ++db) {
      u16x4 o4;
      o4.x = f2bf(od[t][db][0] * inv);
      o4.y = f2bf(od[t][db][1] * inv);
      o4.z = f2bf(od[t][db][2] * inv);
      o4.w = f2bf(od[t][db][3] * inv);
      *(u16x4*)&op[db * 16 + quad * 4] = o4;
    }
  }
}

extern "C" void kernel_launch(void* const* d_in, const int* in_sizes, int n_in,
                              void* d_out, int out_size, void* d_ws, size_t ws_size,
                              hipStream_t stream) {
  const float* x = (const float*)d_in[0];
  const int* pos = (const int*)d_in[1];
  const float* Wq = (const float*)d_in[2];
  const float* Wk = (const float*)d_in[3];
  const float* Wv = (const float*)d_in[4];
  const float* Wo = (const float*)d_in[5];
  float* out = (float*)d_out;

  char* w = (char*)d_ws;
  size_t o = 0;
  auto take = [&](size_t nbytes) {
    char* p = w + o;
    o += (nbytes + 255) & ~(size_t)255;
    return p;
  };
  const size_t actBytes = (size_t)BATCH * S_LEN * DMODEL * 2;
  const size_t wBytes = (size_t)DMODEL * DMODEL * 2;
  u16* xb   = (u16*)take(actBytes);
  u16* Wcat = (u16*)take(3 * wBytes);  // [3072][1024] = Wq;Wk;Wv
  u16* Wob  = (u16*)take(wBytes);
  u16* qb   = (u16*)take(actBytes);
  u16* kb   = (u16*)take(actBytes);
  u16* vt   = (u16*)take(actBytes);  // [B,H,DK,S]
  u16* ab   = (u16*)take(actBytes);

  // Fused casts: x + 4 weight matrices in one launch.
  int ncast = NX4 + 4 * NW4;  // 3145728, exact multiple of 256
  cast_all<<<ncast / 256, 256, 0, stream>>>(x, Wq, Wk, Wv, Wo, xb, Wcat, Wob);

  // Fused QKV: [8192,1024] x [3072,1024]^T
  gemm128<<<dim3(BATCH * S_LEN / 128, 3 * DMODEL / 128), 256, 0, stream>>>(
      xb, Wcat, qb, kb, vt, nullptr, 0);

  int npair = BATCH * S_LEN * DMODEL / 2;
  rope_qk<<<(npair + 255) / 256, 256, 0, stream>>>(qb, kb, pos);

  attn3<<<dim3(8, BATCH * NHEAD), 512, 0, stream>>>(qb, kb, vt, ab);

  gemm128<<<dim3(BATCH * S_LEN / 128, DMODEL / 128), 256, 0, stream>>>(
      ab, Wob, nullptr, nullptr, nullptr, out, 2);
}

// Round 4
// 261.716 us; speedup vs baseline: 1.1307x; 1.1042x over previous
//
#include <hip/hip_runtime.h>

// B=4, S=2048, D=1024, H=16, DK=64. RoPE (interleaved pairs) + causal MHA.
// R3: attention rewrite — no-max softmax, K=16 PV MFMA, merged (qt,31-qt)
// q-tile pairs, SCALE folded into q at RoPE.
// R4: attn3 double-buffered K/V prefetch + XCD-grouping block remap.
// R5: gemm128 2-phase pipeline (dbuf LDS, prefetch-before-compute).
// R6: attn3 512-thread blocks owning two q-tile pairs; fused cast_all.
// R7 (this round):
//  - gemm128 block order reverted to natural (R5's XCD chunk caused 4x L2
//    fill traffic, 49->200MB: each XCD swept all of A per n-panel. Problem
//    is L3-fit; default order + L3 handles reuse).
//  - RoPE fused into QKV gemm epilogue via precomputed cos/sin table
//    (rope_tab kernel, 2048x32 float2, L2-resident): kills the 134MB
//    q/k round-trip and the per-element powf/sincosf. rope_qk deleted.

typedef unsigned short u16;
typedef unsigned int u32;
typedef __attribute__((ext_vector_type(8))) short bf16x8;
typedef __attribute__((ext_vector_type(4))) short bf16x4;
typedef __attribute__((ext_vector_type(4))) float f32x4;
typedef __attribute__((ext_vector_type(4))) unsigned short u16x4;

#define S_LEN 2048
#define DMODEL 1024
#define NHEAD 16
#define DKH 64
#define BATCH 4
#define NT 32  // S_LEN/64 key tiles
#define NX4 (BATCH * S_LEN * DMODEL / 4)  // 2097152
#define NW4 (DMODEL * DMODEL / 4)         // 262144 = 2^18

static __device__ __forceinline__ u16 f2bf(float f) {
  union { float f; u32 u; } v; v.f = f;
  u32 r = v.u + 0x7fffu + ((v.u >> 16) & 1u);  // RNE
  return (u16)(r >> 16);
}
#if __has_builtin(__builtin_amdgcn_cvt_pk_bf16_f32)
typedef __attribute__((ext_vector_type(2))) __bf16 bf2_t;
static __device__ __forceinline__ u32 pack2bf(float a, float b) {
  union { bf2_t h; u32 u; } cv;
  cv.h = __builtin_amdgcn_cvt_pk_bf16_f32(a, b);
  return cv.u;
}
#else
static __device__ __forceinline__ u32 pack2bf(float a, float b) {
  return (u32)f2bf(a) | ((u32)f2bf(b) << 16);
}
#endif
static __device__ __forceinline__ float fexp2(float x) {
#if __has_builtin(__builtin_amdgcn_exp2f)
  return __builtin_amdgcn_exp2f(x);
#else
  return exp2f(x);
#endif
}
static __device__ __forceinline__ f32x4 mfma16(bf16x8 a, bf16x8 b, f32x4 c) {
  return __builtin_amdgcn_mfma_f32_16x16x32_bf16(a, b, c, 0, 0, 0);
}
#if __has_builtin(__builtin_amdgcn_mfma_f32_16x16x16bf16_1k)
#define HAVE_MFMA_K16 1
static __device__ __forceinline__ f32x4 mfma16k16(bf16x4 a, bf16x4 b, f32x4 c) {
  return __builtin_amdgcn_mfma_f32_16x16x16bf16_1k(a, b, c, 0, 0, 0);
}
#else
#define HAVE_MFMA_K16 0
#endif
// Async global->LDS, 16B per lane. LDS dest = wave-uniform base + lane*16.
static __device__ __forceinline__ void glds16(const void* g, void* l) {
  __builtin_amdgcn_global_load_lds((const __attribute__((address_space(1))) u32*)g,
                                   (__attribute__((address_space(3))) u32*)l, 16, 0, 0);
}

// One fused cast pass: x (8M f32) + Wq,Wk,Wv -> Wcat + Wo -> Wob.
__global__ __launch_bounds__(256) void cast_all(const float* __restrict__ x,
                                                const float* __restrict__ Wq,
                                                const float* __restrict__ Wk,
                                                const float* __restrict__ Wv,
                                                const float* __restrict__ Wo,
                                                u16* __restrict__ xb,
                                                u16* __restrict__ Wcat,
                                                u16* __restrict__ Wob) {
  int i = blockIdx.x * 256 + threadIdx.x;
  const float* s;
  u16* d;
  if (i < NX4) {
    s = x + (size_t)i * 4;
    d = xb + (size_t)i * 4;
  } else {
    int j = i - NX4;
    int r = j >> 18;
    int off = j & (NW4 - 1);
    const float* W = r == 0 ? Wq : r == 1 ? Wk : r == 2 ? Wv : Wo;
    s = W + (size_t)off * 4;
    d = (r < 3 ? Wcat + (size_t)r * DMODEL * DMODEL : Wob) + (size_t)off * 4;
  }
  u16x4 o;
  o.x = f2bf(s[0]); o.y = f2bf(s[1]); o.z = f2bf(s[2]); o.w = f2bf(s[3]);
  *(u16x4*)d = o;
}

// cos/sin table for RoPE: tab[s*32+p] = {cos, sin}(pos[s] * 10000^(-2p/64)).
__global__ __launch_bounds__(256) void rope_tab(const int* __restrict__ pos,
                                                float2* __restrict__ tab) {
  int i = blockIdx.x * 256 + threadIdx.x;  // over 2048*32
  int s = i >> 5, p = i & 31;
  float ph = (float)pos[s] * powf(10000.0f, -(float)(2 * p) / 64.0f);
  float sn, cs;
  sincosf(ph, &sn, &cs);
  tab[i] = make_float2(cs, sn);
}

// C[m,n] = sum_k A[m,k] * W[n,k]. 128x128 tile, BK=64, glds staging,
// 2-phase double-buffered pipeline: stage tile kt+1 into buf^1 BEFORE the
// MFMA phase on buf; single __syncthreads per K-step.
// mode 0: QKV epilogue with fused RoPE (n<1024 -> q rot+scale -> oq,
//         <2048 -> k rot -> ok, else v -> ov as [B,H,DK,S]).
// mode 2: fp32 store to of.
__global__ __launch_bounds__(256) void gemm128(const u16* __restrict__ A,
                                               const u16* __restrict__ W,
                                               u16* __restrict__ oq,
                                               u16* __restrict__ ok,
                                               u16* __restrict__ ov,
                                               float* __restrict__ of,
                                               const float2* __restrict__ tab,
                                               int mode) {
  __shared__ __attribute__((aligned(16))) u16 As[2][128 * 64];
  __shared__ __attribute__((aligned(16))) u16 Bs[2][128 * 64];
  const int m0 = blockIdx.x * 128, n0 = blockIdx.y * 128;
  const int tid = threadIdx.x, lane = tid & 63, wave = tid >> 6;
  const int quad = lane >> 4, c = lane & 15;
  const int wm = (wave & 1) * 64, wn = (wave >> 1) * 64;
  const int ls = lane >> 3, lc = lane & 7;

  auto stage = [&](int buf, int ko) {
#pragma unroll
    for (int i = 0; i < 4; ++i) {
      int rb = i * 32 + wave * 8;
      int r = rb + ls;
      int kA = ko + 8 * (lc ^ (r & 7));
      glds16(&A[(size_t)(m0 + r) * DMODEL + kA], &As[buf][rb * 64]);
      glds16(&W[(size_t)(n0 + r) * DMODEL + kA], &Bs[buf][rb * 64]);
    }
  };

  f32x4 acc[4][4] = {};
  stage(0, 0);
  __syncthreads();
#pragma unroll 1
  for (int kt = 0; kt < DMODEL / 64; ++kt) {
    const int cur = kt & 1;
    if (kt < DMODEL / 64 - 1) stage(cur ^ 1, (kt + 1) * 64);  // prefetch, no wait
#pragma unroll
    for (int t = 0; t < 2; ++t) {
      bf16x8 af[4], bfr[4];
#pragma unroll
      for (int mb = 0; mb < 4; ++mb) {
        int r = wm + mb * 16 + c;
        af[mb] = *(const bf16x8*)&As[cur][r * 64 + 8 * ((t * 4 + quad) ^ (r & 7))];
      }
#pragma unroll
      for (int nb = 0; nb < 4; ++nb) {
        int r = wn + nb * 16 + c;
        bfr[nb] = *(const bf16x8*)&Bs[cur][r * 64 + 8 * ((t * 4 + quad) ^ (r & 7))];
      }
#pragma unroll
      for (int mb = 0; mb < 4; ++mb)
#pragma unroll
        for (int nb = 0; nb < 4; ++nb)
          acc[mb][nb] = mfma16(af[mb], bfr[nb], acc[mb][nb]);
    }
    __syncthreads();  // vmcnt(0)+barrier: prefetched buffer ready for kt+1
  }
#pragma unroll
  for (int mb = 0; mb < 4; ++mb) {
    int mrow = m0 + wm + mb * 16 + quad * 4;
#pragma unroll
    for (int nb = 0; nb < 4; ++nb) {
      int n = n0 + wn + nb * 16 + c;
      f32x4 v = acc[mb][nb];
      if (mode == 2) {
#pragma unroll
        for (int r = 0; r < 4; ++r) of[(size_t)(mrow + r) * DMODEL + n] = v[r];
      } else if (n < 2 * DMODEL) {
        // fused RoPE: pair partner (d^1) is in neighbor lane (c parity == d
        // parity: n0/wn/nb*16 all even). Wave-uniform branch region.
        const bool isq = n < DMODEL;
        const int p = (n & 63) >> 1;  // pair index within head
        const bool odd = n & 1;
        u16* dst = isq ? oq : ok;
        const int ncol = n & (DMODEL - 1);
#pragma unroll
        for (int r = 0; r < 4; ++r) {
          float v1 = v[r];
          float v2 = __shfl_xor(v1, 1);
          float x1 = odd ? v2 : v1;
          float x2 = odd ? v1 : v2;
          int s = (mrow + r) & (S_LEN - 1);
          float2 t2 = tab[s * 32 + p];
          float rv = odd ? (x1 * t2.y + x2 * t2.x) : (x1 * t2.x - x2 * t2.y);
          if (isq) rv *= 0.18033688011112042f;  // 0.125 * log2(e)
          dst[(size_t)(mrow + r) * DMODEL + ncol] = f2bf(rv);
        }
      } else {
        int nn = n - 2 * DMODEL;
        int h = nn >> 6, d = nn & 63;
        int b = mrow >> 11, s = mrow & (S_LEN - 1);
        u16x4 p4;
        p4.x = f2bf(v[0]); p4.y = f2bf(v[1]); p4.z = f2bf(v[2]); p4.w = f2bf(v[3]);
        *(u16x4*)&ov[((size_t)(b * NHEAD + h) * DKH + d) * S_LEN + s] = p4;
      }
    }
  }
}

// Flash attention, S^T formulation, no-max softmax.
// Grid (8, B*H), 512 threads. Block handles TWO merged q-tile pairs:
//   waves 0-3: pair A = (2x, 31-2x)    (33 applies)
//   waves 4-7: pair B = (2x+1, 30-2x)  (33 applies, idle only at j=J)
// One K/V tile staged per iteration feeds both pairs. XCD remap keeps each
// (b,h)'s 8 blocks on one XCD (L2-resident K/V). Complementary-x tail
// balance. setprio(1) around MFMA clusters.
__global__ __launch_bounds__(512) void attn3(const u16* __restrict__ qb,
                                             const u16* __restrict__ kb,
                                             const u16* __restrict__ vt,
                                             u16* __restrict__ ab) {
  __shared__ __attribute__((aligned(16))) u16 Ks[2][64 * 64];  // [key][d] swizzled
  __shared__ __attribute__((aligned(16))) u16 Vs[2][64 * 64];  // [d][key] swizzled
  // 512 blocks total; XCD = L%8; 8 blocks per (b,h), 8 (b,h) per XCD.
  const int L = blockIdx.x + 8 * blockIdx.y;
  const int xcd = L & 7, slot = L >> 3;   // slot in [0,64)
  const int bhl = slot >> 3;              // local head in [0,8)
  const int xs = slot & 7;
  const int x = (bhl & 4) ? 7 - xs : xs;  // complementary-x tail balance
  const int bh = xcd * 8 + bhl;
  const int b = bh >> 4, h = bh & 15;
  const int tid = threadIdx.x, lane = tid & 63, wave = tid >> 6;
  const int g = wave >> 2;   // 0: pair A, 1: pair B
  const int w4 = wave & 3;   // q-col group within tile
  const int quad = lane >> 4, c = lane & 15;
  const int ls = lane >> 3, lc = lane & 7;
  const int wq = w4 * 16;
  const int qtl = 2 * x + g, qth = 31 - 2 * x - g;
  const int J = 31 - 2 * x;  // loop bound = pair A's qt2
  const float NEG = -3.0e38f;

  bf16x8 qf[2][2];
#pragma unroll
  for (int t = 0; t < 2; ++t) {
    int qrow = (t ? qth : qtl) * 64 + wq + c;
    const u16* qp = qb + (size_t)(b * S_LEN + qrow) * DMODEL + h * DKH;
    qf[t][0] = *(const bf16x8*)&qp[quad * 8];
    qf[t][1] = *(const bf16x8*)&qp[32 + quad * 8];
  }
  float li[2] = {0.f, 0.f};
  f32x4 od[2][4] = {};

  // stage tile j into buffer buf: 8 waves x 8 rows each (K and V), no wait
  auto stage = [&](int buf, int j) {
    int r = wave * 8 + ls;
    int col = 8 * (lc ^ (r & 7));
    glds16(&kb[(size_t)(b * S_LEN + j * 64 + r) * DMODEL + h * DKH + col],
           &Ks[buf][wave * 8 * 64]);
    glds16(&vt[((size_t)bh * DKH + r) * S_LEN + j * 64 + col],
           &Vs[buf][wave * 8 * 64]);
  };

  // one q-tile application against the K/V tile staged in buffer cur
  auto apply = [&](int t, int cur, bool diag) {
    f32x4 sc[4];
    __builtin_amdgcn_s_setprio(1);
#pragma unroll
    for (int kbi = 0; kbi < 4; ++kbi) {
      int r = kbi * 16 + c;
      bf16x8 k0 = *(const bf16x8*)&Ks[cur][r * 64 + 8 * (quad ^ (r & 7))];
      bf16x8 k1 = *(const bf16x8*)&Ks[cur][r * 64 + 8 * ((4 + quad) ^ (r & 7))];
      f32x4 a = {};
      a = mfma16(k0, qf[t][0], a);
      a = mfma16(k1, qf[t][1], a);
      sc[kbi] = a;  // already log2-domain (q pre-scaled)
    }
    __builtin_amdgcn_s_setprio(0);
    if (diag) {
#pragma unroll
      for (int kbi = 0; kbi < 4; ++kbi)
#pragma unroll
        for (int r = 0; r < 4; ++r)
          if (kbi * 16 + quad * 4 + r > wq + c) sc[kbi][r] = NEG;
    }
    float rs = 0.f;
#pragma unroll
    for (int kbi = 0; kbi < 4; ++kbi)
#pragma unroll
      for (int r = 0; r < 4; ++r) {
        float p = fexp2(sc[kbi][r]);
        sc[kbi][r] = p;
        rs += p;
      }
    rs += __shfl_xor(rs, 16);
    rs += __shfl_xor(rs, 32);
    li[t] += rs;
#if HAVE_MFMA_K16
    // pk[kbi] = keys kbi*16+quad*4+{0,1,2,3} for q-col c == 16x16x16 B-frag
    bf16x4 pkv[4];
#pragma unroll
    for (int kbi = 0; kbi < 4; ++kbi) {
      union { u32 w[2]; bf16x4 v; } pk;
      pk.w[0] = pack2bf(sc[kbi][0], sc[kbi][1]);
      pk.w[1] = pack2bf(sc[kbi][2], sc[kbi][3]);
      pkv[kbi] = pk.v;
    }
    __builtin_amdgcn_s_setprio(1);
#pragma unroll
    for (int db = 0; db < 4; ++db) {
      int r = db * 16 + c;
#pragma unroll
      for (int kbi = 0; kbi < 4; ++kbi) {
        int g2 = kbi * 2 + (quad >> 1);
        bf16x4 vf = *(const bf16x4*)&Vs[cur][r * 64 + 8 * (g2 ^ (r & 7)) + (quad & 1) * 4];
        od[t][db] = mfma16k16(vf, pkv[kbi], od[t][db]);
      }
    }
    __builtin_amdgcn_s_setprio(0);
#else
    // fallback: shuffle P^T into K=32 B-frag layout
    u32 pk[4][2];
#pragma unroll
    for (int kbi = 0; kbi < 4; ++kbi) {
      pk[kbi][0] = pack2bf(sc[kbi][0], sc[kbi][1]);
      pk[kbi][1] = pack2bf(sc[kbi][2], sc[kbi][3]);
    }
    const int s0 = ((quad & 1) * 2) * 16 + c;
    const int s1 = s0 + 16;
    const bool hi = quad >= 2;
#pragma unroll
    for (int base = 0; base < 2; ++base) {
      u32 e0 = __shfl(pk[base * 2][0], s0);
      u32 e1 = __shfl(pk[base * 2][1], s0);
      u32 e2 = __shfl(pk[base * 2][0], s1);
      u32 e3 = __shfl(pk[base * 2][1], s1);
      u32 o0 = __shfl(pk[base * 2 + 1][0], s0);
      u32 o1 = __shfl(pk[base * 2 + 1][1], s0);
      u32 o2 = __shfl(pk[base * 2 + 1][0], s1);
      u32 o3 = __shfl(pk[base * 2 + 1][1], s1);
      union { u32 w[4]; bf16x8 v; } pf;
      pf.w[0] = hi ? o0 : e0;
      pf.w[1] = hi ? o1 : e1;
      pf.w[2] = hi ? o2 : e2;
      pf.w[3] = hi ? o3 : e3;
#pragma unroll
      for (int db = 0; db < 4; ++db) {
        int r = db * 16 + c;
        bf16x8 vf = *(const bf16x8*)&Vs[cur][r * 64 + 8 * ((base * 4 + quad) ^ (c & 7))];
        od[t][db] = mfma16(vf, pf.v, od[t][db]);
      }
    }
#endif
  };

  // prologue: stage tile 0 into buffer 0, wait (syncthreads drains vmcnt)
  stage(0, 0);
  __syncthreads();
#pragma unroll 1
  for (int j = 0; j <= J; ++j) {
    int cur = j & 1;
    if (j < J) stage(cur ^ 1, j + 1);  // prefetch next tile, no wait
    if (j <= qtl) apply(0, cur, j == qtl);
    if (j <= qth) apply(1, cur, j == qth);
    __syncthreads();  // vmcnt(0)+lgkmcnt(0)+barrier: next buffer ready
  }

#pragma unroll
  for (int t = 0; t < 2; ++t) {
    float inv = 1.0f / li[t];
    int qrow = (t ? qth : qtl) * 64 + wq + c;
    u16* op = ab + (size_t)(b * S_LEN + qrow) * DMODEL + h * DKH;
#pragma unroll
    for (int db = 0; db < 4; ++db) {
      u16x4 o4;
      o4.x = f2bf(od[t][db][0] * inv);
      o4.y = f2bf(od[t][db][1] * inv);
      o4.z = f2bf(od[t][db][2] * inv);
      o4.w = f2bf(od[t][db][3] * inv);
      *(u16x4*)&op[db * 16 + quad * 4] = o4;
    }
  }
}

extern "C" void kernel_launch(void* const* d_in, const int* in_sizes, int n_in,
                              void* d_out, int out_size, void* d_ws, size_t ws_size,
                              hipStream_t stream) {
  const float* x = (const float*)d_in[0];
  const int* pos = (const int*)d_in[1];
  const float* Wq = (const float*)d_in[2];
  const float* Wk = (const float*)d_in[3];
  const float* Wv = (const float*)d_in[4];
  const float* Wo = (const float*)d_in[5];
  float* out = (float*)d_out;

  char* w = (char*)d_ws;
  size_t o = 0;
  auto take = [&](size_t nbytes) {
    char* p = w + o;
    o += (nbytes + 255) & ~(size_t)255;
    return p;
  };
  const size_t actBytes = (size_t)BATCH * S_LEN * DMODEL * 2;
  const size_t wBytes = (size_t)DMODEL * DMODEL * 2;
  u16* xb   = (u16*)take(actBytes);
  u16* Wcat = (u16*)take(3 * wBytes);  // [3072][1024] = Wq;Wk;Wv
  u16* Wob  = (u16*)take(wBytes);
  u16* qb   = (u16*)take(actBytes);
  u16* kb   = (u16*)take(actBytes);
  u16* vt   = (u16*)take(actBytes);  // [B,H,DK,S]
  u16* ab   = (u16*)take(actBytes);
  float2* tab = (float2*)take((size_t)S_LEN * 32 * sizeof(float2));

  // Fused casts: x + 4 weight matrices in one launch.
  int ncast = NX4 + 4 * NW4;  // 3145728, exact multiple of 256
  cast_all<<<ncast / 256, 256, 0, stream>>>(x, Wq, Wk, Wv, Wo, xb, Wcat, Wob);

  // RoPE cos/sin table: 2048 x 32 pairs.
  rope_tab<<<(S_LEN * 32) / 256, 256, 0, stream>>>(pos, tab);

  // Fused QKV: [8192,1024] x [3072,1024]^T, RoPE fused in epilogue.
  gemm128<<<dim3(BATCH * S_LEN / 128, 3 * DMODEL / 128), 256, 0, stream>>>(
      xb, Wcat, qb, kb, vt, nullptr, tab, 0);

  attn3<<<dim3(8, BATCH * NHEAD), 512, 0, stream>>>(qb, kb, vt, ab);

  gemm128<<<dim3(BATCH * S_LEN / 128, DMODEL / 128), 256, 0, stream>>>(
      ab, Wob, nullptr, nullptr, nullptr, out, nullptr, 2);
}